// Round 7
// baseline (483.821 us; speedup 1.0000x reference)
//
#include <hip/hip_runtime.h>

#define HID 128
#define WFRAG (HID*HID)   // 16384 fragment elements per layer

typedef __attribute__((ext_vector_type(8))) short bf16x8;
typedef __attribute__((ext_vector_type(4))) float f32x4;

static __device__ __forceinline__ unsigned short f2bf(float f){
  unsigned u = __float_as_uint(f);
  unsigned r = (u + 0x7FFF + ((u >> 16) & 1)) >> 16;   // RNE
  return (unsigned short)r;
}
static __device__ __forceinline__ float bf2f_lo(unsigned u){ return __uint_as_float(u << 16); }
static __device__ __forceinline__ float bf2f_hi(unsigned u){ return __uint_as_float(u & 0xFFFF0000u); }

static __device__ __forceinline__ unsigned cvtpk(float lo, float hi){
  unsigned r;
  asm volatile("v_cvt_pk_bf16_f32 %0, %1, %2" : "=v"(r) : "v"(lo), "v"(hi));
  return r;
}

__global__ __launch_bounds__(256) void k_count_deg(const int* __restrict__ dst, int* __restrict__ deg, int E){
  int e = blockIdx.x*256 + threadIdx.x;
  if (e < E) atomicAdd(&deg[dst[e]], 1);
}

// Per-block inclusive scan of deg + one global-cursor bump; emits dinv too.
__global__ __launch_bounds__(256) void k_alloc(const int* __restrict__ deg, int* __restrict__ rowstart,
                                               float* __restrict__ dinv, int* __restrict__ cursor, int N){
  __shared__ int sm[256];
  __shared__ int sbase;
  int t = threadIdx.x;
  int n = blockIdx.x*256 + t;
  int d = (n < N) ? deg[n] : 0;
  sm[t] = d;
  __syncthreads();
  for (int off = 1; off < 256; off <<= 1){
    int v = (t >= off) ? sm[t-off] : 0;
    __syncthreads();
    sm[t] += v;
    __syncthreads();
  }
  if (t == 255) sbase = atomicAdd(cursor, sm[255]);
  __syncthreads();
  if (n < N){
    rowstart[n] = sbase + sm[t] - d;
    dinv[n] = d > 0 ? rsqrtf((float)d) : 0.0f;
  }
}

// Slots hold ONLY src (4B): norm factored as dinv[n]*(sum dinv[src]*h[src]),
// dinv[src] folded into H by the gemm epilogue, dinv[n] applied post-loop.
// Halves the cross-XCD partial-line flush traffic (R6: WRITE=E*64B).
__global__ __launch_bounds__(256) void k_fill(const int* __restrict__ src, const int* __restrict__ dst,
                                              const int* __restrict__ rowstart,
                                              int* __restrict__ fill, int* __restrict__ slots, int E){
  int e = blockIdx.x*256 + threadIdx.x;
  if (e >= E) return;
  int s = src[e], d = dst[e];
  int p = atomicAdd(&fill[d], 1);
  slots[rowstart[d] + p] = s;
}

// Decompose W (f32 [k][n]) into MFMA B-fragment-layout bf16 hi/lo tables.
// Frag layout (mfma_f32_16x16x32_bf16): B col=lane&15, k=8*(lane>>4)+j.
__global__ __launch_bounds__(256) void k_wprep(const float* __restrict__ Ws, unsigned short* __restrict__ Whi,
                                               unsigned short* __restrict__ Wlo){
  int layer = blockIdx.x;
  const float* W = Ws + (size_t)layer*HID*HID;
  for (int idx = threadIdx.x; idx < 2048; idx += 256){
    int lane = idx & 63, kstep = (idx>>6)&3, nblk = idx>>8;
    int col = 16*nblk + (lane&15);
    int k0  = 32*kstep + 8*(lane>>4);
    size_t obase = ((size_t)(layer*8 + nblk)*4 + kstep)*512 + (size_t)lane*8;
    for (int j = 0; j < 8; j++){
      float v = W[(size_t)(k0+j)*HID + col];
      unsigned short h = f2bf(v);
      float hf = __uint_as_float((unsigned)h << 16);
      Whi[obase+j] = h;
      Wlo[obase+j] = f2bf(v - hf);
    }
  }
}

// H' = dinv[row] * (X @ W), split-precision bf16 MFMA, H' stored bf16.
// 32 rows x 128 cols per block; wave w owns cols [32w,32w+32).
__global__ __launch_bounds__(256) void k_gemm_mfma(const float* __restrict__ X, const unsigned short* __restrict__ Whi,
                                                   const unsigned short* __restrict__ Wlo,
                                                   const float* __restrict__ dinv,
                                                   unsigned short* __restrict__ H2u, int N){
  int t = threadIdx.x, w = t>>6, l = t&63;
  int row0 = blockIdx.x*32;
  int lrow = l & 15, lk = (l>>4)*8;
  f32x4 acc[2][2] = {};
#pragma unroll 1
  for (int kstep = 0; kstep < 4; kstep++){
    bf16x8 ahi[2], alo[2];
#pragma unroll
    for (int m = 0; m < 2; m++){
      int row = row0 + 16*m + lrow;
      if (row >= N) row = N-1;
      const float* ap = X + (size_t)row*HID + kstep*32 + lk;
      float4 a0 = *(const float4*)ap;
      float4 a1 = *(const float4*)(ap+4);
      int4 hh, ll;
      hh.x = cvtpk(a0.x, a0.y); hh.y = cvtpk(a0.z, a0.w);
      hh.z = cvtpk(a1.x, a1.y); hh.w = cvtpk(a1.z, a1.w);
      ll.x = cvtpk(a0.x - bf2f_lo(hh.x), a0.y - bf2f_hi(hh.x));
      ll.y = cvtpk(a0.z - bf2f_lo(hh.y), a0.w - bf2f_hi(hh.y));
      ll.z = cvtpk(a1.x - bf2f_lo(hh.z), a1.y - bf2f_hi(hh.z));
      ll.w = cvtpk(a1.z - bf2f_lo(hh.w), a1.w - bf2f_hi(hh.w));
      ahi[m] = *(bf16x8*)&hh;
      alo[m] = *(bf16x8*)&ll;
    }
    bf16x8 bhi[2], blo[2];
#pragma unroll
    for (int n = 0; n < 2; n++){
      size_t base = ((size_t)((2*w+n)*4 + kstep))*512 + (size_t)l*8;
      bhi[n] = *(const bf16x8*)(Whi + base);
      blo[n] = *(const bf16x8*)(Wlo + base);
    }
#pragma unroll
    for (int m = 0; m < 2; m++)
#pragma unroll
      for (int n = 0; n < 2; n++){
        acc[m][n] = __builtin_amdgcn_mfma_f32_16x16x32_bf16(ahi[m], bhi[n], acc[m][n], 0, 0, 0);
        acc[m][n] = __builtin_amdgcn_mfma_f32_16x16x32_bf16(alo[m], bhi[n], acc[m][n], 0, 0, 0);
        acc[m][n] = __builtin_amdgcn_mfma_f32_16x16x32_bf16(ahi[m], blo[n], acc[m][n], 0, 0, 0);
      }
  }
  // D: row=4*(lane>>4)+r, col=lane&15
#pragma unroll
  for (int m = 0; m < 2; m++)
#pragma unroll
    for (int r = 0; r < 4; r++){
      int row = row0 + 16*m + 4*(l>>4) + r;
      if (row < N){
        float dv = dinv[row];
#pragma unroll
        for (int n = 0; n < 2; n++){
          int col = 16*(2*w+n) + lrow;
          H2u[(size_t)row*HID + col] = f2bf(dv * acc[m][n][r]);
        }
      }
    }
}

// One wave per node; lane holds one bf16x2 (2 cols). 16-deep gather pipeline;
// no per-edge weight (pre-scaled H'), dinv[n] applied after the loop.
__global__ __launch_bounds__(256) void k_agg(const unsigned int* __restrict__ H2, const int* __restrict__ slots,
                                             const int* __restrict__ rowstart, const int* __restrict__ deg,
                                             const float* __restrict__ dinv,
                                             const float* __restrict__ bias, float* __restrict__ out, int N){
  int wid = threadIdx.x >> 6, lane = threadIdx.x & 63;
  int n = blockIdx.x*4 + wid;
  if (n >= N) return;
  int st = rowstart[n], cnt = deg[n];
  float a0 = 0.f, a1 = 0.f;
  int j = 0;
  for (; j + 16 <= cnt; j += 16){
    int sl[16];
#pragma unroll
    for (int q = 0; q < 16; q++) sl[q] = slots[st+j+q];
    unsigned hv[16];
#pragma unroll
    for (int q = 0; q < 16; q++) hv[q] = H2[(size_t)sl[q]*(HID/2) + lane];
#pragma unroll
    for (int q = 0; q < 16; q++){
      a0 += bf2f_lo(hv[q]);
      a1 += bf2f_hi(hv[q]);
    }
  }
  for (; j < cnt; j++){
    int sl = slots[st + j];
    unsigned hv = H2[(size_t)sl*(HID/2) + lane];
    a0 += bf2f_lo(hv);
    a1 += bf2f_hi(hv);
  }
  float dv = dinv[n];
  float2 b = *(const float2*)(bias + lane*2);
  float2 o; o.x = dv*a0 + b.x; o.y = dv*a1 + b.y;
  *(float2*)(out + (size_t)n*HID + lane*2) = o;
}

extern "C" void kernel_launch(void* const* d_in, const int* in_sizes, int n_in,
                              void* d_out, int out_size, void* d_ws, size_t ws_size,
                              hipStream_t stream){
  const float* x  = (const float*)d_in[0];
  const int*   ei = (const int*)d_in[1];
  const float* Ws = (const float*)d_in[2];
  const float* bs = (const float*)d_in[3];
  const int N = in_sizes[0] / HID;
  const int E = in_sizes[1] / 2;
  const int L = in_sizes[2] / (HID*HID);
  const int* src = ei;        // edge_index[0]
  const int* dst = ei + E;    // edge_index[1]

  char* w = (char*)d_ws;
  int*   deg      = (int*)w;   w += (size_t)N*4;
  int*   fill     = (int*)w;   w += (size_t)N*4;
  int*   cursor   = (int*)w;   w += 16;
  size_t zbytes = (size_t)(w - (char*)d_ws);       // deg + fill + cursor must be zeroed
  float* dinv     = (float*)w; w += (size_t)N*4;
  int*   rowstart = (int*)w;   w += (size_t)N*4;
  int*   slots    = (int*)w;   w += (size_t)E*4;
  unsigned short* h2u = (unsigned short*)w; w += (size_t)N*HID*2;
  unsigned short* whi = (unsigned short*)w; w += (size_t)L*WFRAG*2;
  unsigned short* wlo = (unsigned short*)w; w += (size_t)L*WFRAG*2;

  hipMemsetAsync(d_ws, 0, zbytes, stream);

  int gE = (E + 255)/256, gN = (N + 255)/256;
  k_count_deg<<<gE, 256, 0, stream>>>(dst, deg, E);
  k_alloc   <<<gN, 256, 0, stream>>>(deg, rowstart, dinv, cursor, N);
  k_wprep   <<<L,  256, 0, stream>>>(Ws, whi, wlo);
  k_fill    <<<gE, 256, 0, stream>>>(src, dst, rowstart, fill, slots, E);

  const float* xin = x;
  float* out = (float*)d_out;
  for (int l = 0; l < L; l++){
    k_gemm_mfma<<<(N + 31)/32, 256, 0, stream>>>(xin, whi + (size_t)l*WFRAG, wlo + (size_t)l*WFRAG,
                                                 dinv, h2u, N);
    k_agg<<<(N + 3)/4, 256, 0, stream>>>((const unsigned int*)h2u, slots, rowstart, deg,
                                         dinv, bs + (size_t)l*HID, out, N);
    xin = out;
  }
}

// Round 8
// 452.175 us; speedup vs baseline: 1.0700x; 1.0700x over previous
//
#include <hip/hip_runtime.h>

#define HID 128
#define WFRAG (HID*HID)   // 16384 fragment elements per layer
#define NPASS 8

typedef __attribute__((ext_vector_type(8))) short bf16x8;
typedef __attribute__((ext_vector_type(4))) float f32x4;

static __device__ __forceinline__ unsigned short f2bf(float f){
  unsigned u = __float_as_uint(f);
  unsigned r = (u + 0x7FFF + ((u >> 16) & 1)) >> 16;   // RNE
  return (unsigned short)r;
}
static __device__ __forceinline__ float bf2f_lo(unsigned u){ return __uint_as_float(u << 16); }
static __device__ __forceinline__ float bf2f_hi(unsigned u){ return __uint_as_float(u & 0xFFFF0000u); }

static __device__ __forceinline__ unsigned cvtpk(float lo, float hi){
  unsigned r;
  asm volatile("v_cvt_pk_bf16_f32 %0, %1, %2" : "=v"(r) : "v"(lo), "v"(hi));
  return r;
}

// Histogram of dst, restricted to [lo,hi): 8 range passes keep the atomic
// footprint (50KB) L2-resident per pass (R7: full-range scatter was
// temporal-locality-free -> 64B flush per 4-8B write).
__global__ __launch_bounds__(256) void k_hist(const int* __restrict__ dst, int* __restrict__ deg,
                                              int E, int lo, int hi){
  int e = blockIdx.x*256 + threadIdx.x;
  if (e < E){
    int d = dst[e];
    if (d >= lo && d < hi) atomicAdd(&deg[d], 1);
  }
}

// Deterministic 3-step scan: per-block sums -> single-block scan -> rowstart.
__global__ __launch_bounds__(256) void k_bsum(const int* __restrict__ deg, int* __restrict__ bsum, int N){
  __shared__ int sm[256];
  int t = threadIdx.x, n = blockIdx.x*256 + t;
  sm[t] = (n < N) ? deg[n] : 0;
  __syncthreads();
  for (int off = 128; off > 0; off >>= 1){
    if (t < off) sm[t] += sm[t+off];
    __syncthreads();
  }
  if (t == 0) bsum[blockIdx.x] = sm[0];
}

__global__ __launch_bounds__(512) void k_scan1(const int* __restrict__ bsum, int* __restrict__ bbase, int nb){
  __shared__ int sm[512];
  int t = threadIdx.x;
  int v = (t < nb) ? bsum[t] : 0;
  sm[t] = v;
  __syncthreads();
  for (int off = 1; off < 512; off <<= 1){
    int u = (t >= off) ? sm[t-off] : 0;
    __syncthreads();
    sm[t] += u;
    __syncthreads();
  }
  if (t < nb) bbase[t] = sm[t] - v;   // exclusive
}

__global__ __launch_bounds__(256) void k_rowstart(const int* __restrict__ deg, const int* __restrict__ bbase,
                                                  int* __restrict__ rowstart, float* __restrict__ dinv, int N){
  __shared__ int sm[256];
  int t = threadIdx.x, n = blockIdx.x*256 + t;
  int d = (n < N) ? deg[n] : 0;
  sm[t] = d;
  __syncthreads();
  for (int off = 1; off < 256; off <<= 1){
    int v = (t >= off) ? sm[t-off] : 0;
    __syncthreads();
    sm[t] += v;
    __syncthreads();
  }
  if (n < N){
    rowstart[n] = bbase[blockIdx.x] + sm[t] - d;
    dinv[n] = d > 0 ? rsqrtf((float)d) : 0.0f;
  }
}

// CSR fill, range-passed like k_hist; slots hold only src (norm folded into
// H' by gemm epilogue + post-scale in agg).
__global__ __launch_bounds__(256) void k_fill(const int* __restrict__ src, const int* __restrict__ dst,
                                              const int* __restrict__ rowstart,
                                              int* __restrict__ fill, int* __restrict__ slots,
                                              int E, int lo, int hi){
  int e = blockIdx.x*256 + threadIdx.x;
  if (e >= E) return;
  int d = dst[e];
  if (d < lo || d >= hi) return;
  int p = atomicAdd(&fill[d], 1);
  slots[rowstart[d] + p] = src[e];
}

// Decompose W (f32 [k][n]) into MFMA B-fragment-layout bf16 hi/lo tables.
// Frag layout (mfma_f32_16x16x32_bf16): B col=lane&15, k=8*(lane>>4)+j.
__global__ __launch_bounds__(256) void k_wprep(const float* __restrict__ Ws, unsigned short* __restrict__ Whi,
                                               unsigned short* __restrict__ Wlo){
  int layer = blockIdx.x;
  const float* W = Ws + (size_t)layer*HID*HID;
  for (int idx = threadIdx.x; idx < 2048; idx += 256){
    int lane = idx & 63, kstep = (idx>>6)&3, nblk = idx>>8;
    int col = 16*nblk + (lane&15);
    int k0  = 32*kstep + 8*(lane>>4);
    size_t obase = ((size_t)(layer*8 + nblk)*4 + kstep)*512 + (size_t)lane*8;
    for (int j = 0; j < 8; j++){
      float v = W[(size_t)(k0+j)*HID + col];
      unsigned short h = f2bf(v);
      float hf = __uint_as_float((unsigned)h << 16);
      Whi[obase+j] = h;
      Wlo[obase+j] = f2bf(v - hf);
    }
  }
}

// H' = dinv[row] * (X @ W), split-precision bf16 MFMA, H' stored bf16.
__global__ __launch_bounds__(256) void k_gemm_mfma(const float* __restrict__ X, const unsigned short* __restrict__ Whi,
                                                   const unsigned short* __restrict__ Wlo,
                                                   const float* __restrict__ dinv,
                                                   unsigned short* __restrict__ H2u, int N){
  int t = threadIdx.x, w = t>>6, l = t&63;
  int row0 = blockIdx.x*32;
  int lrow = l & 15, lk = (l>>4)*8;
  f32x4 acc[2][2] = {};
#pragma unroll 1
  for (int kstep = 0; kstep < 4; kstep++){
    bf16x8 ahi[2], alo[2];
#pragma unroll
    for (int m = 0; m < 2; m++){
      int row = row0 + 16*m + lrow;
      if (row >= N) row = N-1;
      const float* ap = X + (size_t)row*HID + kstep*32 + lk;
      float4 a0 = *(const float4*)ap;
      float4 a1 = *(const float4*)(ap+4);
      int4 hh, ll;
      hh.x = cvtpk(a0.x, a0.y); hh.y = cvtpk(a0.z, a0.w);
      hh.z = cvtpk(a1.x, a1.y); hh.w = cvtpk(a1.z, a1.w);
      ll.x = cvtpk(a0.x - bf2f_lo(hh.x), a0.y - bf2f_hi(hh.x));
      ll.y = cvtpk(a0.z - bf2f_lo(hh.y), a0.w - bf2f_hi(hh.y));
      ll.z = cvtpk(a1.x - bf2f_lo(hh.z), a1.y - bf2f_hi(hh.z));
      ll.w = cvtpk(a1.z - bf2f_lo(hh.w), a1.w - bf2f_hi(hh.w));
      ahi[m] = *(bf16x8*)&hh;
      alo[m] = *(bf16x8*)&ll;
    }
    bf16x8 bhi[2], blo[2];
#pragma unroll
    for (int n = 0; n < 2; n++){
      size_t base = ((size_t)((2*w+n)*4 + kstep))*512 + (size_t)l*8;
      bhi[n] = *(const bf16x8*)(Whi + base);
      blo[n] = *(const bf16x8*)(Wlo + base);
    }
#pragma unroll
    for (int m = 0; m < 2; m++)
#pragma unroll
      for (int n = 0; n < 2; n++){
        acc[m][n] = __builtin_amdgcn_mfma_f32_16x16x32_bf16(ahi[m], bhi[n], acc[m][n], 0, 0, 0);
        acc[m][n] = __builtin_amdgcn_mfma_f32_16x16x32_bf16(alo[m], bhi[n], acc[m][n], 0, 0, 0);
        acc[m][n] = __builtin_amdgcn_mfma_f32_16x16x32_bf16(ahi[m], blo[n], acc[m][n], 0, 0, 0);
      }
  }
  // D: row=4*(lane>>4)+r, col=lane&15
#pragma unroll
  for (int m = 0; m < 2; m++)
#pragma unroll
    for (int r = 0; r < 4; r++){
      int row = row0 + 16*m + 4*(l>>4) + r;
      if (row < N){
        float dv = dinv[row];
#pragma unroll
        for (int n = 0; n < 2; n++){
          int col = 16*(2*w+n) + lrow;
          H2u[(size_t)row*HID + col] = f2bf(dv * acc[m][n][r]);
        }
      }
    }
}

// One wave per node; lane holds one bf16x2 (2 cols).
// 8-deep PREDICATED batches for ALL edges incl. tail (R7 lesson: 16-deep main
// + scalar tail collapsed MLP for the ~46% of nodes with deg<16).
// Clamped index overreads <=28B past a node's range (pad slots by 8 ints).
__global__ __launch_bounds__(256) void k_agg(const unsigned int* __restrict__ H2, const int* __restrict__ slots,
                                             const int* __restrict__ rowstart, const int* __restrict__ deg,
                                             const float* __restrict__ dinv,
                                             const float* __restrict__ bias, float* __restrict__ out, int N){
  int wid = threadIdx.x >> 6, lane = threadIdx.x & 63;
  int n = blockIdx.x*4 + wid;
  if (n >= N) return;
  int st = rowstart[n], cnt = deg[n];
  float a0 = 0.f, a1 = 0.f;
  for (int j = 0; j < cnt; j += 8){
    int ix[8];
#pragma unroll
    for (int q = 0; q < 8; q++){
      int jj = j + q;
      jj = jj < cnt ? jj : cnt - 1;
      ix[q] = slots[st + jj];
    }
    unsigned hv[8];
#pragma unroll
    for (int q = 0; q < 8; q++) hv[q] = H2[(size_t)ix[q]*(HID/2) + lane];
#pragma unroll
    for (int q = 0; q < 8; q++){
      bool v = (j + q) < cnt;
      a0 += v ? bf2f_lo(hv[q]) : 0.f;
      a1 += v ? bf2f_hi(hv[q]) : 0.f;
    }
  }
  float dv = dinv[n];
  float2 b = *(const float2*)(bias + lane*2);
  float2 o; o.x = dv*a0 + b.x; o.y = dv*a1 + b.y;
  *(float2*)(out + (size_t)n*HID + lane*2) = o;
}

extern "C" void kernel_launch(void* const* d_in, const int* in_sizes, int n_in,
                              void* d_out, int out_size, void* d_ws, size_t ws_size,
                              hipStream_t stream){
  const float* x  = (const float*)d_in[0];
  const int*   ei = (const int*)d_in[1];
  const float* Ws = (const float*)d_in[2];
  const float* bs = (const float*)d_in[3];
  const int N = in_sizes[0] / HID;
  const int E = in_sizes[1] / 2;
  const int L = in_sizes[2] / (HID*HID);
  const int* src = ei;        // edge_index[0]
  const int* dst = ei + E;    // edge_index[1]
  const int NB = (N + 255)/256;

  char* w = (char*)d_ws;
  int*   deg      = (int*)w;   w += (size_t)N*4;
  int*   fill     = (int*)w;   w += (size_t)N*4;
  size_t zbytes = (size_t)(w - (char*)d_ws);       // deg + fill must be zeroed
  int*   bsum     = (int*)w;   w += (size_t)NB*4;
  int*   bbase    = (int*)w;   w += (size_t)NB*4;
  float* dinv     = (float*)w; w += (size_t)N*4;
  int*   rowstart = (int*)w;   w += (size_t)N*4;
  int*   slots    = (int*)w;   w += (size_t)E*4 + 64;   // +pad for clamped overread
  unsigned short* h2u = (unsigned short*)w; w += (size_t)N*HID*2;
  unsigned short* whi = (unsigned short*)w; w += (size_t)L*WFRAG*2;
  unsigned short* wlo = (unsigned short*)w; w += (size_t)L*WFRAG*2;

  hipMemsetAsync(d_ws, 0, zbytes, stream);

  int gE = (E + 255)/256;
  int R = (N + NPASS - 1)/NPASS;
  for (int p = 0; p < NPASS; p++){
    int lo = p*R, hi = lo + R < N ? lo + R : N;
    k_hist<<<gE, 256, 0, stream>>>(dst, deg, E, lo, hi);
  }
  k_bsum    <<<NB, 256, 0, stream>>>(deg, bsum, N);
  k_scan1   <<<1, 512, 0, stream>>>(bsum, bbase, NB);
  k_rowstart<<<NB, 256, 0, stream>>>(deg, bbase, rowstart, dinv, N);
  k_wprep   <<<L,  256, 0, stream>>>(Ws, whi, wlo);
  for (int p = 0; p < NPASS; p++){
    int lo = p*R, hi = lo + R < N ? lo + R : N;
    k_fill<<<gE, 256, 0, stream>>>(src, dst, rowstart, fill, slots, E, lo, hi);
  }

  const float* xin = x;
  float* out = (float*)d_out;
  for (int l = 0; l < L; l++){
    k_gemm_mfma<<<(N + 31)/32, 256, 0, stream>>>(xin, whi + (size_t)l*WFRAG, wlo + (size_t)l*WFRAG,
                                                 dinv, h2u, N);
    k_agg<<<(N + 3)/4, 256, 0, stream>>>((const unsigned int*)h2u, slots, rowstart, deg,
                                         dinv, bs + (size_t)l*HID, out, N);
    xin = out;
  }
}